// Round 1
// baseline (528.243 us; speedup 1.0000x reference)
//
#include <hip/hip_runtime.h>
#include <math.h>

// ---------- types ----------
using short8  = __attribute__((ext_vector_type(8))) short;   // 8 x bf16 (4 VGPRs)
using floatx4 = __attribute__((ext_vector_type(4))) float;   // MFMA accumulator

#define DEVI __device__ __forceinline__

// Problem constants
#define BATCH 2
#define SEQ   4096
#define NE    512      // n_embd
#define NH    8
#define HD    64
#define MTOT  8192     // BATCH*SEQ

DEVI short f2bf(float f) {
    unsigned u = __builtin_bit_cast(unsigned, f);
    unsigned r = (u + 0x7fffu + ((u >> 16) & 1u)) >> 16;   // RNE
    return (short)r;
}

DEVI void async16(const void* g, void* l) {
    __builtin_amdgcn_global_load_lds(
        (const __attribute__((address_space(1))) void*)g,
        (__attribute__((address_space(3))) void*)l, 16, 0, 0);
}

// ---------- fp32 -> bf16 conversion ----------
__global__ __launch_bounds__(256) void cvt_bf16(const float* __restrict__ src,
                                                short* __restrict__ dst, int n4) {
    int i = blockIdx.x * 256 + threadIdx.x;
    if (i >= n4) return;
    float4 f = ((const float4*)src)[i];
    short4 o;
    o.x = f2bf(f.x); o.y = f2bf(f.y); o.z = f2bf(f.z); o.w = f2bf(f.w);
    ((short4*)dst)[i] = o;
}

// ---------- shared GEMM mainloop: C[m,n] = sum_k A[m,k] * W[n,k] ----------
// 128x128 tile, BK=64, 256 threads = 4 waves (2x2), each wave 64x64 via 4x4 MFMAs.
DEVI void gemm_mainloop(const short* __restrict__ A, const short* __restrict__ W,
                        int m0, int n0, short* ldsA, short* ldsW, floatx4 (&acc)[4][4]) {
    const int tid  = threadIdx.x;
    const int lane = tid & 63;
    const int w    = tid >> 6;
    const int wm   = w >> 1, wn = w & 1;
    const int quad = lane >> 4, l15 = lane & 15;
    const int srow = lane >> 3, scol = (lane & 7) * 8;

    for (int i = 0; i < 4; ++i)
        for (int j = 0; j < 4; ++j)
            acc[i][j] = floatx4{0.f, 0.f, 0.f, 0.f};

    for (int kt = 0; kt < NE / 64; ++kt) {
        const int k0 = kt * 64;
        // stage A-tile and W-tile: wave w covers rows w*32 .. w*32+31, 8 rows/call
        for (int c = 0; c < 4; ++c) {
            const int rb = w * 32 + c * 8;
            async16(A + (size_t)(m0 + rb + srow) * NE + k0 + scol, ldsA + rb * 64);
            async16(W + (size_t)(n0 + rb + srow) * NE + k0 + scol, ldsW + rb * 64);
        }
        __syncthreads();
        for (int ks = 0; ks < 2; ++ks) {
            short8 af[4], bf[4];
            for (int i = 0; i < 4; ++i)
                af[i] = *(const short8*)(ldsA + (wm * 64 + i * 16 + l15) * 64 + ks * 32 + quad * 8);
            for (int j = 0; j < 4; ++j)
                bf[j] = *(const short8*)(ldsW + (wn * 64 + j * 16 + l15) * 64 + ks * 32 + quad * 8);
            for (int i = 0; i < 4; ++i)
                for (int j = 0; j < 4; ++j)
                    acc[i][j] = __builtin_amdgcn_mfma_f32_16x16x32_bf16(af[i], bf[j], acc[i][j], 0, 0, 0);
        }
        __syncthreads();
    }
}

// ---------- QKV GEMM: writes q/k/v bf16 in [B, H, T, HD] ----------
__global__ __launch_bounds__(256) void gemm_qkv(const short* __restrict__ xbf,
                                                const short* __restrict__ wbf,
                                                const float* __restrict__ bq,
                                                const float* __restrict__ bk,
                                                const float* __restrict__ bv,
                                                short* __restrict__ qkv) {
    __shared__ short ldsA[128 * 64];
    __shared__ short ldsW[128 * 64];
    const int m0 = blockIdx.x * 128, n0 = blockIdx.y * 128, z = blockIdx.z;
    const short* W = wbf + (size_t)z * (NE * NE);
    const float* bias = (z == 0) ? bq : (z == 1) ? bk : bv;
    short* out = qkv + (size_t)z * (MTOT * NE);

    floatx4 acc[4][4];
    gemm_mainloop(xbf, W, m0, n0, ldsA, ldsW, acc);

    const int lane = threadIdx.x & 63, w = threadIdx.x >> 6;
    const int wm = w >> 1, wn = w & 1, quad = lane >> 4, l15 = lane & 15;
    for (int j = 0; j < 4; ++j) {
        const int col = n0 + wn * 64 + j * 16 + l15;
        const float bz = bias[col];
        const int h = col >> 6, d = col & 63;
        for (int i = 0; i < 4; ++i) {
            for (int r = 0; r < 4; ++r) {
                const int row = m0 + wm * 64 + i * 16 + quad * 4 + r;
                const int b = row >> 12, t = row & 4095;
                const float v = acc[i][j][r] + bz;
                out[(((size_t)(b * NH + h)) * SEQ + t) * HD + d] = f2bf(v);
            }
        }
    }
}

// ---------- projection GEMM: fp32 out [MTOT, NE] ----------
__global__ __launch_bounds__(256) void gemm_proj(const short* __restrict__ ybf,
                                                 const short* __restrict__ wp,
                                                 const float* __restrict__ bp,
                                                 float* __restrict__ out) {
    __shared__ short ldsA[128 * 64];
    __shared__ short ldsW[128 * 64];
    const int m0 = blockIdx.x * 128, n0 = blockIdx.y * 128;

    floatx4 acc[4][4];
    gemm_mainloop(ybf, wp, m0, n0, ldsA, ldsW, acc);

    const int lane = threadIdx.x & 63, w = threadIdx.x >> 6;
    const int wm = w >> 1, wn = w & 1, quad = lane >> 4, l15 = lane & 15;
    for (int j = 0; j < 4; ++j) {
        const int col = n0 + wn * 64 + j * 16 + l15;
        const float bz = bp[col];
        for (int i = 0; i < 4; ++i) {
            for (int r = 0; r < 4; ++r) {
                const int row = m0 + wm * 64 + i * 16 + quad * 4 + r;
                out[(size_t)row * NE + col] = acc[i][j][r] + bz;
            }
        }
    }
}

// ---------- flash attention (causal), bf16 in/out, fp32 softmax ----------
// grid = (SEQ/64, BATCH*NH); block = 256 (4 waves). Each wave owns 16 Q rows.
__global__ __launch_bounds__(256) void attn(const short* __restrict__ q,
                                            const short* __restrict__ k,
                                            const short* __restrict__ v,
                                            short* __restrict__ y) {
    const int qt = blockIdx.x;
    const int bh = blockIdx.y;
    const int tid = threadIdx.x, lane = tid & 63, w = tid >> 6;
    const int quad = lane >> 4, l15 = lane & 15;

    __shared__ short ldsK[64 * 64];     // K tile [j][d]
    __shared__ short ldsV[64 * 64];     // V tile transposed: [d][j]
    __shared__ short ldsP[4 * 16 * 64]; // per-wave P round-trip

    const size_t headoff = (size_t)bh * (SEQ * HD);
    const short* Q = q + headoff + (size_t)qt * 64 * HD;
    const short* K = k + headoff;
    const short* V = v + headoff;

    // Q fragments: A-operand layout, rows w*16+l15, loaded once from global
    short8 qfrag[2];
    for (int ks = 0; ks < 2; ++ks)
        qfrag[ks] = *(const short8*)&Q[(w * 16 + l15) * HD + ks * 32 + quad * 8];

    floatx4 O[4];
    for (int n = 0; n < 4; ++n) O[n] = floatx4{0.f, 0.f, 0.f, 0.f};
    float mrow[4], lrow[4];
    for (int r = 0; r < 4; ++r) { mrow[r] = -3.0e38f; lrow[r] = 0.f; }

    const int srow8 = lane >> 3, scol = (lane & 7) * 8;
    const float csc = 0.18033688011112042f;  // (1/sqrt(64)) * log2(e)

    for (int jt = 0; jt <= qt; ++jt) {
        const short* Kt = K + (size_t)jt * 64 * HD;
        const short* Vt = V + (size_t)jt * 64 * HD;

        // stage K tile: wave w covers rows w*16 .. w*16+15
        for (int c = 0; c < 2; ++c) {
            const int rb = w * 16 + c * 8;
            async16(Kt + (rb + srow8) * HD + scol, ldsK + rb * 64);
        }
        // stage V tile transposed (manual)
        for (int s0 = 0; s0 < 2; ++s0) {
            const int s = tid + s0 * 256;         // 0..511
            const int j = s >> 3, dblk = (s & 7) * 8;
            short8 vv = *(const short8*)&Vt[j * HD + dblk];
            for (int e = 0; e < 8; ++e) ldsV[(dblk + e) * 64 + j] = vv[e];
        }
        __syncthreads();

        // S = Q Kt^T  (16 rows x 64 cols per wave)
        floatx4 S[4];
        for (int n = 0; n < 4; ++n) S[n] = floatx4{0.f, 0.f, 0.f, 0.f};
        for (int ks = 0; ks < 2; ++ks) {
            for (int n = 0; n < 4; ++n) {
                short8 kf = *(const short8*)(ldsK + (n * 16 + l15) * 64 + ks * 32 + quad * 8);
                S[n] = __builtin_amdgcn_mfma_f32_16x16x32_bf16(qfrag[ks], kf, S[n], 0, 0, 0);
            }
        }

        // scale (+ causal mask on diagonal tile)
        if (jt == qt) {
            for (int n = 0; n < 4; ++n)
                for (int r = 0; r < 4; ++r) {
                    const int rowl = w * 16 + quad * 4 + r;
                    const int coll = n * 16 + l15;
                    S[n][r] = (coll <= rowl) ? S[n][r] * csc : -3.0e38f;
                }
        } else {
            for (int n = 0; n < 4; ++n)
                for (int r = 0; r < 4; ++r) S[n][r] *= csc;
        }

        // online softmax, per row r (16 lanes share a row)
        for (int r = 0; r < 4; ++r) {
            float mx = fmaxf(fmaxf(S[0][r], S[1][r]), fmaxf(S[2][r], S[3][r]));
            for (int off = 1; off < 16; off <<= 1)
                mx = fmaxf(mx, __shfl_xor(mx, off, 64));
            const float mnew = fmaxf(mrow[r], mx);
            const float alpha = exp2f(mrow[r] - mnew);
            float sum = 0.f;
            for (int n = 0; n < 4; ++n) {
                const float p = exp2f(S[n][r] - mnew);
                S[n][r] = p;
                sum += p;
            }
            for (int off = 1; off < 16; off <<= 1)
                sum += __shfl_xor(sum, off, 64);
            lrow[r] = lrow[r] * alpha + sum;
            mrow[r] = mnew;
            for (int n = 0; n < 4; ++n) O[n][r] *= alpha;
        }

        // P (C/D layout) -> LDS -> A-operand layout, bf16
        short* myP = ldsP + w * (16 * 64);
        for (int n = 0; n < 4; ++n)
            for (int r = 0; r < 4; ++r)
                myP[(quad * 4 + r) * 64 + n * 16 + l15] = f2bf(S[n][r]);
        short8 pfrag[2];
        for (int ks = 0; ks < 2; ++ks)
            pfrag[ks] = *(const short8*)(myP + l15 * 64 + ks * 32 + quad * 8);

        // O += P @ V   (B-operand from transposed V: contiguous along j)
        for (int ks = 0; ks < 2; ++ks) {
            for (int n = 0; n < 4; ++n) {
                short8 vf = *(const short8*)(ldsV + (n * 16 + l15) * 64 + ks * 32 + quad * 8);
                O[n] = __builtin_amdgcn_mfma_f32_16x16x32_bf16(pfrag[ks], vf, O[n], 0, 0, 0);
            }
        }
        __syncthreads();
    }

    // epilogue: y[b, t, h*64+d] bf16, normalized by lrow
    const int b = bh >> 3, h = bh & 7;
    for (int r = 0; r < 4; ++r) {
        const float inv = 1.0f / lrow[r];
        const int t = qt * 64 + w * 16 + quad * 4 + r;
        for (int n = 0; n < 4; ++n) {
            const int col = h * 64 + n * 16 + l15;
            y[((size_t)(b * SEQ + t)) * NE + col] = f2bf(O[n][r] * inv);
        }
    }
}

// ---------- host launch ----------
extern "C" void kernel_launch(void* const* d_in, const int* in_sizes, int n_in,
                              void* d_out, int out_size, void* d_ws, size_t ws_size,
                              hipStream_t stream) {
    const float* x  = (const float*)d_in[0];
    const float* Wq = (const float*)d_in[3];
    const float* bq = (const float*)d_in[4];
    const float* Wk = (const float*)d_in[5];
    const float* bk = (const float*)d_in[6];
    const float* Wv = (const float*)d_in[7];
    const float* bv = (const float*)d_in[8];
    const float* Wp = (const float*)d_in[9];
    const float* bp = (const float*)d_in[10];
    float* out = (float*)d_out;

    // ws layout (shorts)
    short* ws   = (short*)d_ws;
    short* xbf  = ws;                           // 8192*512      = 4,194,304
    short* wbf  = xbf + (size_t)MTOT * NE;      // 4 * 512*512   = 1,048,576
    short* qb   = wbf + 4 * (size_t)NE * NE;    // q,k,v each 4,194,304
    short* kb   = qb + (size_t)MTOT * NE;
    short* vb   = kb + (size_t)MTOT * NE;
    short* yb   = vb + (size_t)MTOT * NE;       // attention output bf16

    // convert x + weights to bf16
    cvt_bf16<<<(MTOT * NE / 4 + 255) / 256, 256, 0, stream>>>(x, xbf, MTOT * NE / 4);
    cvt_bf16<<<(NE * NE / 4 + 255) / 256, 256, 0, stream>>>(Wq, wbf + 0 * (size_t)NE * NE, NE * NE / 4);
    cvt_bf16<<<(NE * NE / 4 + 255) / 256, 256, 0, stream>>>(Wk, wbf + 1 * (size_t)NE * NE, NE * NE / 4);
    cvt_bf16<<<(NE * NE / 4 + 255) / 256, 256, 0, stream>>>(Wv, wbf + 2 * (size_t)NE * NE, NE * NE / 4);
    cvt_bf16<<<(NE * NE / 4 + 255) / 256, 256, 0, stream>>>(Wp, wbf + 3 * (size_t)NE * NE, NE * NE / 4);

    // QKV projections (z = 0,1,2)
    gemm_qkv<<<dim3(MTOT / 128, NE / 128, 3), 256, 0, stream>>>(xbf, wbf, bq, bk, bv, qb);

    // causal flash attention
    attn<<<dim3(SEQ / 64, BATCH * NH), 256, 0, stream>>>(qb, kb, vb, yb);

    // output projection
    gemm_proj<<<dim3(MTOT / 128, NE / 128), 256, 0, stream>>>(yb, wbf + 3 * (size_t)NE * NE, bp, out);
}